// Round 2
// baseline (621.498 us; speedup 1.0000x reference)
//
#include <hip/hip_runtime.h>
#include <hip/hip_bf16.h>
#include <math.h>

typedef unsigned short u16;
typedef __attribute__((ext_vector_type(8))) short bf16x8;
typedef __attribute__((ext_vector_type(8))) unsigned short us8;
typedef __attribute__((ext_vector_type(4))) float f32x4;

static __device__ __forceinline__ u16 f2bf(float f) {
  __hip_bfloat16 h = __float2bfloat16(f);
  return *reinterpret_cast<u16*>(&h);
}

// ---------------------------------------------------------------------------
// K0: x fp32 -> bf16 (288x1024)
// ---------------------------------------------------------------------------
__global__ __launch_bounds__(256) void conv_x(const float* __restrict__ x,
                                              u16* __restrict__ xb) {
  int idx = (blockIdx.x * 256 + threadIdx.x) * 4;
  float4 v = *(const float4*)(x + idx);
  ushort4 o;
  o.x = f2bf(v.x); o.y = f2bf(v.y); o.z = f2bf(v.z); o.w = f2bf(v.w);
  *(ushort4*)(xb + idx) = o;
}

// ---------------------------------------------------------------------------
// K0b: W_proj [1024][150] fp32 -> WT4 [p][160][1024] bf16, pads (j>=150) zero
// ---------------------------------------------------------------------------
__global__ __launch_bounds__(256) void trans_wp(
    const float* __restrict__ W0, const float* __restrict__ W1,
    const float* __restrict__ W2, const float* __restrict__ W3,
    u16* __restrict__ WT4) {
  __shared__ float lds[64 * 151];
  int kt = blockIdx.x, p = blockIdx.y;
  const float* W = (p == 0) ? W0 : (p == 1) ? W1 : (p == 2) ? W2 : W3;
  for (int t = threadIdx.x; t < 64 * 150; t += 256) {
    int k = t / 150, j = t - k * 150;
    lds[k * 151 + j] = W[(size_t)(kt * 64 + k) * 150 + j];
  }
  __syncthreads();
  u16* dst = WT4 + (size_t)p * 160 * 1024 + kt * 64;
  for (int t = threadIdx.x; t < 160 * 64; t += 256) {
    int j = t >> 6, kk = t & 63;
    float v = (j < 150) ? lds[kk * 151 + j] : 0.f;
    dst[(size_t)j * 1024 + kk] = f2bf(v);
  }
}

// ---------------------------------------------------------------------------
// transpose W_tri [600 oi][150 k][150 j] fp32 -> WtT [tri][600][160 j][160 k]
// bf16. grid (600, 2 jhalf, 2 tri). LDS 49.2 KB -> 3 blocks/CU.
// ---------------------------------------------------------------------------
__global__ __launch_bounds__(256) void transw2(const float* __restrict__ Wa,
                                               const float* __restrict__ Wb,
                                               u16* __restrict__ WtT) {
  __shared__ float lds[150 * 82];
  int oi = blockIdx.x, jh = blockIdx.y, tri = blockIdx.z;
  const float* W = tri ? Wb : Wa;
  const float* src = W + (size_t)oi * 22500 + jh * 80;
  for (int t = threadIdx.x; t < 150 * 40; t += 256) {
    int k = t / 40, c = t - k * 40;
    if (jh * 80 + 2 * c < 150) {
      float2 v = *(const float2*)(src + (size_t)k * 150 + 2 * c);
      *(float2*)&lds[k * 82 + 2 * c] = v;
    }
  }
  __syncthreads();
  u16* dst = WtT + (size_t)tri * 15360000 + (size_t)oi * 25600 +
             (size_t)jh * 80 * 160;
  for (int t = threadIdx.x; t < 80 * 20; t += 256) {
    int jl = t / 20, kc = t - jl * 20;
    int j = jh * 80 + jl;
    bool jlive = (j < 150);
    us8 v;
#pragma unroll
    for (int u = 0; u < 8; ++u) {
      int k = kc * 8 + u;
      float f = (jlive && k < 150) ? lds[k * 82 + jl] : 0.f;
      v[u] = f2bf(f);
    }
    *(us8*)(dst + (size_t)jl * 160 + kc * 8) = v;
  }
}

// ---------------------------------------------------------------------------
// Swapped-operand direct-streaming NT-GEMM (no LDS, no barriers).
// M-op rows map to the OUTPUT INNER dim (C rows = quad*4+r -> 4 contiguous
// elements per lane -> packed ushort4 stores). N-op rows map to the outer dim
// (C cols = l16). Block 192 thr = 3 waves; M=80 (5 frags), N=144 (3 waves x
// 3 frags of 16).
// STAGE 0: proj. grid (8 nt over 640 j, 2 over 288 rows).
//   M=WT4 rows j, N=xb rows x, K=1024. C=pAll[p][288][160] (+bias, pad j>=150
//   -> 0).
// STAGE 1: grid (2 nt over 160 j, 1200 oi'=tri*600+oi, 2 b).
//   M=WtT[oi'] rows j, N=sh rows z, K=160. C=wbuf[tri][b][z][o][i][j].
// STAGE 2: grid (2 nt over 160 i, 1152 f2'=tri*576+z*4+o, 2 b).
//   M=wbuf[tri][b][z][o] rows i, N=oh/st rows y, K=160.
//   C=tbuf[tri][b][z][o][y][i].
// ---------------------------------------------------------------------------
template <int STAGE>
__global__ __launch_bounds__(192) void gemm_sw(
    const u16* __restrict__ M0, const u16* __restrict__ N0,
    u16* __restrict__ C, const float* __restrict__ bias0,
    const float* __restrict__ bias1, const float* __restrict__ bias2,
    const float* __restrict__ bias3) {
  constexpr int KS = (STAGE == 0) ? 32 : 5;
  constexpr int SR = (STAGE == 0) ? 1024 : 160;
  const u16* Mb;
  const u16* Nb;
  u16* Cb = nullptr;
  if (STAGE == 0) {
    Mb = M0 + (size_t)blockIdx.x * 80 * 1024;
    Nb = N0 + (size_t)blockIdx.y * 144 * 1024;
  } else if (STAGE == 1) {
    int nt = blockIdx.x, oip = blockIdx.y, b = blockIdx.z;
    int tri = (oip >= 600) ? 1 : 0;
    int oi = oip - tri * 600;
    int o = oi / 150, i = oi - o * 150;
    Mb = M0 + (size_t)oip * 25600 + nt * 12800;
    Nb = N0 + (size_t)b * 23040;
    Cb = C + (size_t)tri * 29491200 + (size_t)b * 14745600 +
         ((size_t)o * 160 + i) * 160 + nt * 80;
  } else {
    int nt = blockIdx.x, f2p = blockIdx.y, b = blockIdx.z;
    int tri = (f2p >= 576) ? 1 : 0;
    int f2 = f2p - tri * 576;
    int z = f2 >> 2, o = f2 & 3;
    Mb = M0 + (size_t)tri * 29491200 + (size_t)b * 14745600 +
         (size_t)z * 102400 + o * 25600 + nt * 12800;
    Nb = N0 + (size_t)(tri ? 46080 : 92160) + (size_t)b * 23040;
    Cb = C + (size_t)tri * 26542080 + (size_t)b * 13271040 +
         (size_t)z * 92160 + o * 23040 + nt * 80;
  }
  int tid = threadIdx.x;
  int lane = tid & 63, wave = tid >> 6;
  int l16 = lane & 15, quad = lane >> 4;
  const u16* Mp = Mb + (size_t)l16 * SR + quad * 8;
  const u16* Np = Nb + (size_t)(wave * 48 + l16) * SR + quad * 8;
  f32x4 acc[5][3];
#pragma unroll
  for (int mi = 0; mi < 5; ++mi)
#pragma unroll
    for (int ni = 0; ni < 3; ++ni) acc[mi][ni] = (f32x4){0.f, 0.f, 0.f, 0.f};

#pragma unroll
  for (int ks = 0; ks < KS; ++ks) {
    bf16x8 mf[5], nf[3];
#pragma unroll
    for (int mi = 0; mi < 5; ++mi)
      mf[mi] = *(const bf16x8*)(Mp + (size_t)mi * 16 * SR + ks * 32);
#pragma unroll
    for (int ni = 0; ni < 3; ++ni)
      nf[ni] = *(const bf16x8*)(Np + (size_t)ni * 16 * SR + ks * 32);
#pragma unroll
    for (int mi = 0; mi < 5; ++mi)
#pragma unroll
      for (int ni = 0; ni < 3; ++ni)
        acc[mi][ni] = __builtin_amdgcn_mfma_f32_16x16x32_bf16(
            mf[mi], nf[ni], acc[mi][ni], 0, 0, 0);
  }

  if (STAGE == 0) {
    int p = blockIdx.x >> 1;
    const float* bp =
        (p == 0) ? bias0 : (p == 1) ? bias1 : (p == 2) ? bias2 : bias3;
    int jb0 = (blockIdx.x & 1) * 80;
#pragma unroll
    for (int mi = 0; mi < 5; ++mi) {
      int jb = jb0 + mi * 16 + quad * 4;
#pragma unroll
      for (int ni = 0; ni < 3; ++ni) {
        int row = blockIdx.y * 144 + wave * 48 + ni * 16 + l16;
        ushort4 pk;
        float v0 = (jb + 0 < 150) ? acc[mi][ni][0] + bp[jb + 0] : 0.f;
        float v1 = (jb + 1 < 150) ? acc[mi][ni][1] + bp[jb + 1] : 0.f;
        float v2 = (jb + 2 < 150) ? acc[mi][ni][2] + bp[jb + 2] : 0.f;
        float v3 = (jb + 3 < 150) ? acc[mi][ni][3] + bp[jb + 3] : 0.f;
        pk.x = f2bf(v0); pk.y = f2bf(v1); pk.z = f2bf(v2); pk.w = f2bf(v3);
        *(ushort4*)(C + ((size_t)p * 288 + row) * 160 + jb) = pk;
      }
    }
  } else {
#pragma unroll
    for (int mi = 0; mi < 5; ++mi) {
      int mb4 = mi * 16 + quad * 4;
#pragma unroll
      for (int ni = 0; ni < 3; ++ni) {
        int outer = wave * 48 + ni * 16 + l16;
        ushort4 pk;
        pk.x = f2bf(acc[mi][ni][0]); pk.y = f2bf(acc[mi][ni][1]);
        pk.z = f2bf(acc[mi][ni][2]); pk.w = f2bf(acc[mi][ni][3]);
        size_t off = (STAGE == 1) ? ((size_t)outer * 102400 + mb4)
                                  : ((size_t)outer * 160 + mb4);
        *(ushort4*)(Cb + off) = pk;
      }
    }
  }
}

// ---------------------------------------------------------------------------
// stage3 + mask + log_softmax. Block 256 = 4 waves (wave = o).
// grid (6 = xtile*2+b, 3 ytile, 144 z). Direct-streaming fragments; LDS only
// for the 4-o epilogue exchange (36.9 KB).
// VAR0: C[x][y] = sum_i st[x,i] * t1[z,o][y][i]
// VAR1: C[x][y] = sum_i t2[z,o][x][i] * ot[y,i]
// ---------------------------------------------------------------------------
template <int VAR>
__global__ __launch_bounds__(256) void stage3_kernel(
    const u16* __restrict__ tb, const u16* __restrict__ P,
    float* __restrict__ out, int BT) {
  __shared__ float sf[9216];
  int bx = blockIdx.x;
  int b = bx & 1, xt = (bx >> 1) * 48;
  int yt = blockIdx.y * 48;
  int zg = blockIdx.z;
  int tid = threadIdx.x;
  const float NL4 = -1.3862943611198906f;
  size_t obase = ((size_t)(b * 144 + zg)) * 82944;
  if (zg > xt + 47) {  // fully masked tile
    float4 v = make_float4(NL4, NL4, NL4, NL4);
    for (int p = tid; p < 2304; p += 256) {
      int xl = p / 48, yl = p - xl * 48;
      *(float4*)(out + obase + ((size_t)(xt + xl) * 144 + yt + yl) * 4) = v;
    }
    return;
  }
  int pbase = (VAR == 0) ? xt : yt;
  int qbase = (VAR == 0) ? yt : xt;
  int lane = tid & 63, o = tid >> 6, l16 = lane & 15, quad = lane >> 4;
  const u16* Pp = P + (size_t)b * 23040 + (size_t)(pbase + l16) * 160 + quad * 8;
  const u16* Tp = tb + (size_t)b * BT + (size_t)zg * 92160 +
                  (size_t)(o * 144 + qbase + l16) * 160 + quad * 8;
  const u16* Ap = (VAR == 0) ? Pp : Tp;  // A side = x rows (both variants)
  const u16* Bp = (VAR == 0) ? Tp : Pp;  // B side = y rows
  f32x4 acc[3][3];
#pragma unroll
  for (int mi = 0; mi < 3; ++mi)
#pragma unroll
    for (int ni = 0; ni < 3; ++ni) acc[mi][ni] = (f32x4){0.f, 0.f, 0.f, 0.f};

#pragma unroll
  for (int ks = 0; ks < 5; ++ks) {
    bf16x8 af[3], bfr[3];
#pragma unroll
    for (int mi = 0; mi < 3; ++mi)
      af[mi] = *(const bf16x8*)(Ap + (size_t)mi * 16 * 160 + ks * 32);
#pragma unroll
    for (int ni = 0; ni < 3; ++ni)
      bfr[ni] = *(const bf16x8*)(Bp + (size_t)ni * 16 * 160 + ks * 32);
#pragma unroll
    for (int mi = 0; mi < 3; ++mi)
#pragma unroll
      for (int ni = 0; ni < 3; ++ni)
        acc[mi][ni] = __builtin_amdgcn_mfma_f32_16x16x32_bf16(
            af[mi], bfr[ni], acc[mi][ni], 0, 0, 0);
  }

#pragma unroll
  for (int mi = 0; mi < 3; ++mi)
#pragma unroll
    for (int ni = 0; ni < 3; ++ni)
#pragma unroll
      for (int r = 0; r < 4; ++r)
        sf[((mi * 16 + quad * 4 + r) * 48 + ni * 16 + l16) * 4 + o] =
            acc[mi][ni][r];
  __syncthreads();
  for (int p = tid; p < 2304; p += 256) {
    int xl = p / 48, yl = p - xl * 48;
    int xg = xt + xl;
    float4 v;
    if (zg > xg) {
      v = make_float4(NL4, NL4, NL4, NL4);
    } else {
      float c0 = sf[p * 4], c1 = sf[p * 4 + 1];
      float c2 = sf[p * 4 + 2], c3 = sf[p * 4 + 3];
      float mx = fmaxf(fmaxf(c0, c1), fmaxf(c2, c3));
      float l = mx + logf(expf(c0 - mx) + expf(c1 - mx) + expf(c2 - mx) +
                          expf(c3 - mx));
      v = make_float4(c0 - l, c1 - l, c2 - l, c3 - l);
    }
    *(float4*)(out + obase + ((size_t)xg * 144 + yt + yl) * 4) = v;
  }
}

// ---------------------------------------------------------------------------
extern "C" void kernel_launch(void* const* d_in, const int* in_sizes, int n_in,
                              void* d_out, int out_size, void* d_ws,
                              size_t ws_size, hipStream_t stream) {
  const float* x = (const float*)d_in[0];
  const float* Wsh = (const float*)d_in[1];
  const float* bsh = (const float*)d_in[2];
  const float* Wst = (const float*)d_in[3];
  const float* bst = (const float*)d_in[4];
  const float* Woh = (const float*)d_in[5];
  const float* boh = (const float*)d_in[6];
  const float* Wot = (const float*)d_in[7];
  const float* bot = (const float*)d_in[8];
  const float* Wt1 = (const float*)d_in[9];
  const float* Wt2 = (const float*)d_in[10];

  u16* ws = (u16*)d_ws;
  u16* xb = ws;                    // 294912
  u16* WT4 = ws + 294912;          // 655360
  u16* pAll = ws + 950272;         // 184320 : [p][288][160]
  u16* WtT = ws + 1134592;         // 2 x 15360000 : [tri][600][160][160]
  u16* wbuf = ws + 31854592;       // 58982400 : [tri][b][144][4][160][160]
  u16* tbuf = ws + 90836992;       // 53084160 : [tri][b][144][4][144][160]
  (void)ws_size;

  conv_x<<<288, 256, 0, stream>>>(x, xb);
  trans_wp<<<dim3(16, 4), 256, 0, stream>>>(Wsh, Wst, Woh, Wot, WT4);
  transw2<<<dim3(600, 2, 2), 256, 0, stream>>>(Wt1, Wt2, WtT);
  gemm_sw<0><<<dim3(8, 2), 192, 0, stream>>>(WT4, xb, pAll, bsh, bst, boh,
                                             bot);
  gemm_sw<1><<<dim3(2, 1200, 2), 192, 0, stream>>>(WtT, pAll, wbuf, nullptr,
                                                   nullptr, nullptr, nullptr);
  gemm_sw<2><<<dim3(2, 1152, 2), 192, 0, stream>>>(wbuf, pAll, tbuf, nullptr,
                                                   nullptr, nullptr, nullptr);

  float* out0 = (float*)d_out;
  float* out1 = out0 + 23887872;  // 2*144^3*4
  stage3_kernel<0><<<dim3(6, 3, 144), 256, 0, stream>>>(
      tbuf, pAll + 46080, out0, 13271040);
  stage3_kernel<1><<<dim3(6, 3, 144), 256, 0, stream>>>(
      tbuf + 26542080, pAll + 138240, out1, 13271040);
}